// Round 1
// 307.535 us; speedup vs baseline: 1.0218x; 1.0218x over previous
//
#include <hip/hip_runtime.h>
#include <hip/hip_bf16.h>

// NeuralODE: y_{s+1} = y_s + DT*(tanh(y W1 + b1) W2 + b2), 250 steps,
// snapshot every 5 -> out[8192][51][128] fp32.
//
// R2: split-m across a 4-wave workgroup. One 16-row tile per 256-thread
// block (512 blocks -> 2048 waves = 8 waves/CU). Wave w computes hidden
// cols [16w,16w+16) of mm1 and output cols [32w,32w+32) of mm2. Y/H tiles
// broadcast through padded LDS; 2 barriers per step. y state stays in
// C-layout fp32 registers so Euler is pure register FMAs.
//
// R3: (a) replace manual round-to-nearest f2bf bit-twiddling (~4 VALU ops
// per value, ~54 VALU/lane/substep total) with native (__bf16) casts so
// the compiler emits v_cvt_pk_bf16_f32 (catalog T12/m240: scalar casts
// beat hand-written asm cvt_pk). (b) split mm1's 4-deep dependent MFMA
// accumulation chain into two 2-deep chains + final add.

typedef __attribute__((ext_vector_type(8))) short bf16x8;   // 8 bf16 = 4 VGPRs
typedef __attribute__((ext_vector_type(4))) float floatx4;

static __device__ __forceinline__ short f2bf(float f) {
    return __builtin_bit_cast(short, (__bf16)f);            // RNE, HW cvt
}

static __device__ __forceinline__ unsigned pack2(float a, float b) {
    // compiler fuses the two casts into one v_cvt_pk_bf16_f32
    unsigned short lo = __builtin_bit_cast(unsigned short, (__bf16)a);
    unsigned short hi = __builtin_bit_cast(unsigned short, (__bf16)b);
    return (unsigned)lo | ((unsigned)hi << 16);
}

static __device__ __forceinline__ float tanh_fast(float x) {
    // tanh(x) = 1 - 2/(1+e^{2x}); exp->inf saturates to +1, exp->0 to -1.
    float e = __expf(2.0f * x);
    return 1.0f - 2.0f * __builtin_amdgcn_rcpf(1.0f + e);
}

#define YP 136   // LDS row stride (bf16) for Y tile: 128 + 8 pad
#define HP 72    // LDS row stride (bf16) for H tile: 64 + 8 pad

__global__ __launch_bounds__(256, 1) void node_kernel(
    const float* __restrict__ x0, const float* __restrict__ W1,
    const float* __restrict__ b1, const float* __restrict__ W2,
    const float* __restrict__ b2, float* __restrict__ out)
{
    __shared__ __align__(16) unsigned short Yld[16 * YP];
    __shared__ __align__(16) unsigned short Hld[16 * HP];

    const int tid  = threadIdx.x;
    const int w    = tid >> 6;          // wave id 0..3 (m-split owner)
    const int lane = tid & 63;
    const int n    = lane & 15;         // MFMA col == row-within-tile
    const int q    = lane >> 4;         // lane quad 0..3
    const int row  = (blockIdx.x << 4) + n;

    // ---- loop-invariant weight A-fragments (this wave's m-slices) ----
    // A-layout: lane holds A[m = 16*tile + n][k = 32*kt + 8*q + j], j=0..7
    bf16x8 w1f[4];                      // mm1: mt = w, kt = 0..3 (K=128)
    #pragma unroll
    for (int kt = 0; kt < 4; ++kt) {
        const int m  = w * 16 + n;
        const int k0 = kt * 32 + q * 8;
        bf16x8 v;
        #pragma unroll
        for (int j = 0; j < 8; ++j) v[j] = f2bf(W1[(k0 + j) * 64 + m]);
        w1f[kt] = v;
    }
    bf16x8 w2f[2][2];                   // mm2: mt = 2w+i, kt = 0..1 (K=64)
    #pragma unroll
    for (int i = 0; i < 2; ++i) {
        #pragma unroll
        for (int kt = 0; kt < 2; ++kt) {
            const int m  = w * 32 + i * 16 + n;
            const int k0 = kt * 32 + q * 8;
            bf16x8 v;
            #pragma unroll
            for (int j = 0; j < 8; ++j) v[j] = f2bf(W2[(k0 + j) * 128 + m]);
            w2f[i][kt] = v;
        }
    }

    // bias fragments in C-layout (row m = 4q+r within this wave's tiles)
    floatx4 b1f, b2f[2];
    #pragma unroll
    for (int r = 0; r < 4; ++r) b1f[r] = b1[w * 16 + q * 4 + r];
    #pragma unroll
    for (int i = 0; i < 2; ++i)
        #pragma unroll
        for (int r = 0; r < 4; ++r) b2f[i][r] = b2[w * 32 + i * 16 + q * 4 + r];

    // ---- y state: this wave's 32 d-columns of the 16-row tile ----
    // y[i][r] = y[d = 32w + 16i + 4q + r][row n]
    floatx4 y[2];
    #pragma unroll
    for (int i = 0; i < 2; ++i)
        #pragma unroll
        for (int r = 0; r < 4; ++r)
            y[i][r] = x0[row * 256 + w * 32 + i * 16 + q * 4 + r];

    // seed Y tile in LDS (bf16 B-operand feed) + t=0 snapshot
    #pragma unroll
    for (int i = 0; i < 2; ++i) {
        uint2 p;
        p.x = pack2(y[i][0], y[i][1]);
        p.y = pack2(y[i][2], y[i][3]);
        *reinterpret_cast<uint2*>(&Yld[n * YP + w * 32 + i * 16 + q * 4]) = p;
        *reinterpret_cast<floatx4*>(out + row * 51 * 128 + w * 32 + i * 16 + q * 4) = y[i];
    }
    __syncthreads();

    for (int ti = 1; ti <= 50; ++ti) {
        #pragma unroll
        for (int ss = 0; ss < 5; ++ss) {
            // ---- mm1 (this wave's 16 hidden cols): h^T = W1^T y^T + b1 ----
            bf16x8 yb[4];
            #pragma unroll
            for (int kt = 0; kt < 4; ++kt)
                yb[kt] = __builtin_bit_cast(bf16x8,
                    *reinterpret_cast<const uint4*>(&Yld[n * YP + kt * 32 + q * 8]));
            // two independent 2-deep accumulation chains (was one 4-deep)
            floatx4 accA = b1f;
            floatx4 accB = {0.0f, 0.0f, 0.0f, 0.0f};
            accA = __builtin_amdgcn_mfma_f32_16x16x32_bf16(w1f[0], yb[0], accA, 0, 0, 0);
            accB = __builtin_amdgcn_mfma_f32_16x16x32_bf16(w1f[1], yb[1], accB, 0, 0, 0);
            accA = __builtin_amdgcn_mfma_f32_16x16x32_bf16(w1f[2], yb[2], accA, 0, 0, 0);
            accB = __builtin_amdgcn_mfma_f32_16x16x32_bf16(w1f[3], yb[3], accB, 0, 0, 0);

            // tanh + pack + stage this wave's H slice
            {
                float t0 = tanh_fast(accA[0] + accB[0]);
                float t1 = tanh_fast(accA[1] + accB[1]);
                float t2 = tanh_fast(accA[2] + accB[2]);
                float t3 = tanh_fast(accA[3] + accB[3]);
                uint2 p;
                p.x = pack2(t0, t1);
                p.y = pack2(t2, t3);
                *reinterpret_cast<uint2*>(&Hld[n * HP + w * 16 + q * 4]) = p;
            }
            __syncthreads();

            // ---- mm2 (this wave's 32 d cols): dy^T = W2^T h^T + b2 ----
            bf16x8 hb[2];
            #pragma unroll
            for (int kt = 0; kt < 2; ++kt)
                hb[kt] = __builtin_bit_cast(bf16x8,
                    *reinterpret_cast<const uint4*>(&Hld[n * HP + kt * 32 + q * 8]));
            floatx4 acc2[2] = { b2f[0], b2f[1] };
            #pragma unroll
            for (int kt = 0; kt < 2; ++kt)
                #pragma unroll
                for (int i = 0; i < 2; ++i)
                    acc2[i] = __builtin_amdgcn_mfma_f32_16x16x32_bf16(
                        w2f[i][kt], hb[kt], acc2[i], 0, 0, 0);

            // Euler update (pure regs) + restage Y slice
            #pragma unroll
            for (int i = 0; i < 2; ++i) {
                #pragma unroll
                for (int r = 0; r < 4; ++r)
                    y[i][r] = fmaf(0.001f, acc2[i][r], y[i][r]);
                uint2 p;
                p.x = pack2(y[i][0], y[i][1]);
                p.y = pack2(y[i][2], y[i][3]);
                *reinterpret_cast<uint2*>(&Yld[n * YP + w * 32 + i * 16 + q * 4]) = p;
            }
            __syncthreads();
        }
        // ---- snapshot every 5 steps ----
        #pragma unroll
        for (int i = 0; i < 2; ++i)
            *reinterpret_cast<floatx4*>(
                out + row * 51 * 128 + ti * 128 + w * 32 + i * 16 + q * 4) = y[i];
    }
}

extern "C" void kernel_launch(void* const* d_in, const int* in_sizes, int n_in,
                              void* d_out, int out_size, void* d_ws, size_t ws_size,
                              hipStream_t stream) {
    const float* x0 = (const float*)d_in[0];
    // d_in[1] = t grid: fixed 51 outputs x 5 substeps, unused
    const float* W1 = (const float*)d_in[2];
    const float* b1 = (const float*)d_in[3];
    const float* W2 = (const float*)d_in[4];
    const float* b2 = (const float*)d_in[5];
    float* out = (float*)d_out;

    node_kernel<<<dim3(512), dim3(256), 0, stream>>>(x0, W1, b1, W2, b2, out);
}

// Round 2
// 262.347 us; speedup vs baseline: 1.1978x; 1.1722x over previous
//
#include <hip/hip_runtime.h>
#include <hip/hip_bf16.h>

// NeuralODE: y_{s+1} = y_s + DT*(tanh(y W1 + b1) W2 + b2), 250 steps,
// snapshot every 5 -> out[8192][51][128] fp32.
//
// R4: hidden-space restructuring. Conjugate the recurrence into the 64-dim
// hidden space: z = y W1 + b1, W21 = W2 W1 (fp32 prologue), c = b2 W1.
//   substep:  a = tanh(z); z += DT*(a @ W21 + c)        [one 64x64 matmul]
//   interval: y += DT*(S @ W2) + 5*DT*b2, S = sum of 5 a's [one K=64 matmul]
// Per substep: 2 MFMA/wave, ONE LDS exchange, ONE barrier (double-buffered
// a tile) vs previous 8 MFMA / 2 exchanges / 2 barriers. The a/S/Y tiles
// use XOR block-swizzle (T2-style, stride 64, no pad) so b128 reads hit
// balanced bank quads (old padded layout was 8-way aliased, 1.85e7
// conflicts/dispatch).

typedef __attribute__((ext_vector_type(8))) short bf16x8;   // 8 bf16 = 4 VGPRs
typedef __attribute__((ext_vector_type(4))) float floatx4;

__device__ float g_w21[64 * 64 + 64];   // W21[hin][hout] (64x64) then c[hout]

static __device__ __forceinline__ short f2bf(float f) {
    return __builtin_bit_cast(short, (__bf16)f);            // RNE, HW cvt
}

static __device__ __forceinline__ unsigned pack2(float a, float b) {
    unsigned short lo = __builtin_bit_cast(unsigned short, (__bf16)a);
    unsigned short hi = __builtin_bit_cast(unsigned short, (__bf16)b);
    return (unsigned)lo | ((unsigned)hi << 16);
}

static __device__ __forceinline__ float tanh_fast(float x) {
    // tanh(x) = 1 - 2/(1+e^{2x}); exp->inf saturates to +1, exp->0 to -1.
    float e = __expf(2.0f * x);
    return 1.0f - 2.0f * __builtin_amdgcn_rcpf(1.0f + e);
}

// ---- prologue: W21 = W2 @ W1 (fp32), c = b2 @ W1 ----
__global__ __launch_bounds__(64) void precompute_kernel(
    const float* __restrict__ W1, const float* __restrict__ W2,
    const float* __restrict__ b2)
{
    const int hout = threadIdx.x;   // 0..63
    const int hin  = blockIdx.x;    // 0..64 (64 == bias row)
    float a0 = 0.f, a1 = 0.f, a2 = 0.f, a3 = 0.f;
    if (hin < 64) {
        #pragma unroll 4
        for (int d = 0; d < 128; d += 4) {
            a0 = fmaf(W2[hin * 128 + d + 0], W1[(d + 0) * 64 + hout], a0);
            a1 = fmaf(W2[hin * 128 + d + 1], W1[(d + 1) * 64 + hout], a1);
            a2 = fmaf(W2[hin * 128 + d + 2], W1[(d + 2) * 64 + hout], a2);
            a3 = fmaf(W2[hin * 128 + d + 3], W1[(d + 3) * 64 + hout], a3);
        }
        g_w21[hin * 64 + hout] = (a0 + a1) + (a2 + a3);
    } else {
        #pragma unroll 4
        for (int d = 0; d < 128; d += 4) {
            a0 = fmaf(b2[d + 0], W1[(d + 0) * 64 + hout], a0);
            a1 = fmaf(b2[d + 1], W1[(d + 1) * 64 + hout], a1);
            a2 = fmaf(b2[d + 2], W1[(d + 2) * 64 + hout], a2);
            a3 = fmaf(b2[d + 3], W1[(d + 3) * 64 + hout], a3);
        }
        g_w21[4096 + hout] = (a0 + a1) + (a2 + a3);
    }
}

__global__ __launch_bounds__(256, 1) void node_kernel(
    const float* __restrict__ x0, const float* __restrict__ W1,
    const float* __restrict__ b1, const float* __restrict__ W2,
    const float* __restrict__ b2, float* __restrict__ out)
{
    // a tile (16 rows x 64 bf16), double-buffered; S tile; y0 seed tile.
    // All stride-64/128 shorts (no pad) + XOR swizzle of 16B blocks by (n&7).
    __shared__ __align__(16) unsigned short Ald[2][16 * 64];
    __shared__ __align__(16) unsigned short Sld[16 * 64];
    __shared__ __align__(16) unsigned short Yld[16 * 128];

    const int tid  = threadIdx.x;
    const int w    = tid >> 6;          // wave id 0..3 (z-col split owner)
    const int lane = tid & 63;
    const int n    = lane & 15;         // MFMA col == batch row within tile
    const int q    = lane >> 4;         // lane quad 0..3
    const int row  = (blockIdx.x << 4) + n;
    const int swz  = n & 7;             // 16B-block XOR swizzle key

    // ---- loop-invariant A-fragments ----
    // z-update: A[m=16w+n][k] = W21[k][m], kt=0..1 (K=64)
    bf16x8 w21f[2];
    #pragma unroll
    for (int kt = 0; kt < 2; ++kt) {
        const int m  = w * 16 + n;
        const int k0 = kt * 32 + q * 8;
        bf16x8 v;
        #pragma unroll
        for (int j = 0; j < 8; ++j) v[j] = f2bf(g_w21[(k0 + j) * 64 + m]);
        w21f[kt] = v;
    }
    // y-update: A[m=32w+16i+n][k=h] = W2[h][m]
    bf16x8 w2f[2][2];
    #pragma unroll
    for (int i = 0; i < 2; ++i) {
        #pragma unroll
        for (int kt = 0; kt < 2; ++kt) {
            const int m  = w * 32 + i * 16 + n;
            const int k0 = kt * 32 + q * 8;
            bf16x8 v;
            #pragma unroll
            for (int j = 0; j < 8; ++j) v[j] = f2bf(W2[(k0 + j) * 128 + m]);
            w2f[i][kt] = v;
        }
    }

    // bias fragments (C-layout, row m = 4q+r of this wave's tiles)
    floatx4 cf, b1f, b2f5[2];
    #pragma unroll
    for (int r = 0; r < 4; ++r) {
        cf[r]  = g_w21[4096 + w * 16 + q * 4 + r];
        b1f[r] = b1[w * 16 + q * 4 + r];
    }
    #pragma unroll
    for (int i = 0; i < 2; ++i)
        #pragma unroll
        for (int r = 0; r < 4; ++r)
            b2f5[i][r] = 5.0f * b2[w * 32 + i * 16 + q * 4 + r];

    // ---- y state: this wave's 32 d-columns of the 16-row tile ----
    floatx4 y[2];
    #pragma unroll
    for (int i = 0; i < 2; ++i)
        #pragma unroll
        for (int r = 0; r < 4; ++r)
            y[i][r] = x0[row * 256 + w * 32 + i * 16 + q * 4 + r];

    // seed Y tile in LDS (swizzled) + t=0 snapshot
    #pragma unroll
    for (int i = 0; i < 2; ++i) {
        const int j0 = 4 * w + 2 * i + (q >> 1);
        uint2 p;
        p.x = pack2(y[i][0], y[i][1]);
        p.y = pack2(y[i][2], y[i][3]);
        *reinterpret_cast<uint2*>(&Yld[n * 128 + (j0 ^ swz) * 8 + (q & 1) * 4]) = p;
        *reinterpret_cast<floatx4*>(out + row * 51 * 128 + w * 32 + i * 16 + q * 4) = y[i];
    }
    __syncthreads();

    // ---- z' = y0 @ W1 + b1 (z' carries b1; a = tanh(z')) ----
    floatx4 z = b1f;
    #pragma unroll
    for (int kt = 0; kt < 4; ++kt) {
        bf16x8 yb = __builtin_bit_cast(bf16x8, *reinterpret_cast<const uint4*>(
            &Yld[n * 128 + ((kt * 4 + q) ^ swz) * 8]));
        const int m  = w * 16 + n;
        const int k0 = kt * 32 + q * 8;
        bf16x8 w1t;
        #pragma unroll
        for (int j = 0; j < 8; ++j) w1t[j] = f2bf(W1[(k0 + j) * 64 + m]);
        z = __builtin_amdgcn_mfma_f32_16x16x32_bf16(w1t, yb, z, 0, 0, 0);
    }

    floatx4 S = {0.0f, 0.0f, 0.0f, 0.0f};

    // LDS short-index addresses (swizzled)
    const int awr  = n * 64 + (((2 * w + (q >> 1)) ^ swz) * 8) + (q & 1) * 4;
    const int ard0 = n * 64 + ((q ^ swz) * 8);
    const int ard1 = n * 64 + (((4 + q) ^ swz) * 8);

    for (int ti = 1; ti <= 50; ++ti) {
        #pragma unroll
        for (int ss = 0; ss < 5; ++ss) {
            const int p = ss & 1;       // a-buffer parity: 0,1,0,1,0
            // a = tanh(z'); S += a; stage a (and S on ss==4)
            float a0 = tanh_fast(z[0]);
            float a1 = tanh_fast(z[1]);
            float a2 = tanh_fast(z[2]);
            float a3 = tanh_fast(z[3]);
            S[0] += a0; S[1] += a1; S[2] += a2; S[3] += a3;
            uint2 pa;
            pa.x = pack2(a0, a1);
            pa.y = pack2(a2, a3);
            *reinterpret_cast<uint2*>(&Ald[p][awr]) = pa;
            if (ss == 4) {
                uint2 ps;
                ps.x = pack2(S[0], S[1]);
                ps.y = pack2(S[2], S[3]);
                *reinterpret_cast<uint2*>(&Sld[awr]) = ps;
            }
            __syncthreads();

            // z' += DT*(a @ W21 + c)
            bf16x8 ab0 = __builtin_bit_cast(bf16x8,
                *reinterpret_cast<const uint4*>(&Ald[p][ard0]));
            bf16x8 ab1 = __builtin_bit_cast(bf16x8,
                *reinterpret_cast<const uint4*>(&Ald[p][ard1]));
            floatx4 acc = cf;
            acc = __builtin_amdgcn_mfma_f32_16x16x32_bf16(w21f[0], ab0, acc, 0, 0, 0);
            acc = __builtin_amdgcn_mfma_f32_16x16x32_bf16(w21f[1], ab1, acc, 0, 0, 0);
            #pragma unroll
            for (int r = 0; r < 4; ++r) z[r] = fmaf(0.001f, acc[r], z[r]);

            if (ss == 4) {
                // y += DT*(S @ W2) + 5*DT*b2 ; snapshot
                bf16x8 sb0 = __builtin_bit_cast(bf16x8,
                    *reinterpret_cast<const uint4*>(&Sld[ard0]));
                bf16x8 sb1 = __builtin_bit_cast(bf16x8,
                    *reinterpret_cast<const uint4*>(&Sld[ard1]));
                floatx4 acc2[2] = { b2f5[0], b2f5[1] };
                #pragma unroll
                for (int i = 0; i < 2; ++i) {
                    acc2[i] = __builtin_amdgcn_mfma_f32_16x16x32_bf16(
                        w2f[i][0], sb0, acc2[i], 0, 0, 0);
                    acc2[i] = __builtin_amdgcn_mfma_f32_16x16x32_bf16(
                        w2f[i][1], sb1, acc2[i], 0, 0, 0);
                }
                #pragma unroll
                for (int i = 0; i < 2; ++i) {
                    #pragma unroll
                    for (int r = 0; r < 4; ++r)
                        y[i][r] = fmaf(0.001f, acc2[i][r], y[i][r]);
                    *reinterpret_cast<floatx4*>(
                        out + row * 51 * 128 + ti * 128 + w * 32 + i * 16 + q * 4) = y[i];
                }
                S = floatx4{0.0f, 0.0f, 0.0f, 0.0f};
                __syncthreads();   // protect Ald[0]/Sld reuse next interval
            }
        }
    }
}

extern "C" void kernel_launch(void* const* d_in, const int* in_sizes, int n_in,
                              void* d_out, int out_size, void* d_ws, size_t ws_size,
                              hipStream_t stream) {
    const float* x0 = (const float*)d_in[0];
    // d_in[1] = t grid: fixed 51 outputs x 5 substeps, unused
    const float* W1 = (const float*)d_in[2];
    const float* b1 = (const float*)d_in[3];
    const float* W2 = (const float*)d_in[4];
    const float* b2 = (const float*)d_in[5];
    float* out = (float*)d_out;

    precompute_kernel<<<dim3(65), dim3(64), 0, stream>>>(W1, W2, b2);
    node_kernel<<<dim3(512), dim3(256), 0, stream>>>(x0, W1, b1, W2, b2, out);
}